// Round 7
// baseline (1040.974 us; speedup 1.0000x reference)
//
#include <hip/hip_runtime.h>
#include <hip/hip_bf16.h>

#define F 128

typedef unsigned int uint;
typedef unsigned short ushort;
typedef __attribute__((ext_vector_type(8))) short short8;   // 8 bf16
typedef __attribute__((ext_vector_type(4))) float f32x4;
typedef __attribute__((ext_vector_type(4))) uint uint4v;    // native vector for nt-load

__device__ inline ushort f2bf(float f) {
    uint u = __float_as_uint(f);
    u += 0x7FFF + ((u >> 16) & 1);   // round-to-nearest-even
    return (ushort)(u >> 16);
}
__device__ inline float2 bf2f(uint u) {
    return make_float2(__uint_as_float(u << 16), __uint_as_float(u & 0xFFFF0000u));
}
// monotone float->uint encoding for atomic min/max
__device__ inline uint fenc(float f) {
    uint u = __float_as_uint(f);
    return (u & 0x80000000u) ? ~u : (u | 0x80000000u);
}
__device__ inline float fdec(uint e) {
    uint u = (e & 0x80000000u) ? (e ^ 0x80000000u) : ~e;
    return __uint_as_float(u);
}

// ---------------- CSR build ----------------
// fused: blocks [0,nbE) do rank (histogram + per-edge rank, one atomic pass);
// blocks [nbE, ...) do prep (x cast + weight frag-major swizzle). Independent work,
// overlapped in one dispatch.
__global__ __launch_bounds__(256) void rank_prep(const int* __restrict__ dst,
                                                 int* __restrict__ cnt,
                                                 ushort* __restrict__ rel, int E, int nbE,
                                                 const float* __restrict__ x,
                                                 const float* __restrict__ W0,
                                                 const float* __restrict__ W1,
                                                 const float* __restrict__ W2,
                                                 const float* __restrict__ W3,
                                                 uint* __restrict__ xb,
                                                 ushort* __restrict__ Wt, int NF4) {
    int b = blockIdx.x;
    if (b < nbE) {
        int e = b * 256 + threadIdx.x;
        if (e < E) rel[e] = (ushort)atomicAdd(&cnt[dst[e]], 1);
        return;
    }
    int i = (b - nbE) * 256 + threadIdx.x;
    if (i < NF4) {
        // non-temporal: x is read once; don't evict the xb gather target from L2
        uint4v u = __builtin_nontemporal_load(((const uint4v*)x) + i);
        uint ua = (uint)f2bf(__uint_as_float(u.x)) | ((uint)f2bf(__uint_as_float(u.y)) << 16);
        uint ub = (uint)f2bf(__uint_as_float(u.z)) | ((uint)f2bf(__uint_as_float(u.w)) << 16);
        ((uint2*)xb)[i] = make_uint2(ua, ub);
    } else {
        int idx = i - NF4;
        if (idx >= 4 * 16384) return;
        int j    = idx & 7;
        int lane = (idx >> 3) & 63;
        int t    = (idx >> 9) & 7;
        int kk   = (idx >> 12) & 3;
        int mat  = idx >> 14;
        int n = 16 * t + (lane & 15);
        int k = 32 * kk + 8 * (lane >> 4) + j;
        const float* W = (mat == 0) ? W0 : (mat == 1) ? W1 : (mat == 2) ? W2 : W3;
        Wt[idx] = f2bf(W[k * 128 + n]);
    }
}

__global__ __launch_bounds__(256) void scan_block(const int* __restrict__ cnt,
                                                  int* __restrict__ off,
                                                  int* __restrict__ bsum, int N) {
    __shared__ int t[256];
    int i = blockIdx.x * 256 + threadIdx.x;
    int v = (i < N) ? cnt[i] : 0;
    t[threadIdx.x] = v;
    __syncthreads();
    for (int o = 1; o < 256; o <<= 1) {
        int x = (threadIdx.x >= o) ? t[threadIdx.x - o] : 0;
        __syncthreads();
        t[threadIdx.x] += x;
        __syncthreads();
    }
    if (i < N) off[i] = t[threadIdx.x] - v;
    if (threadIdx.x == 255) bsum[blockIdx.x] = t[255];
}

__global__ __launch_bounds__(512) void scan_sums(int* __restrict__ bsum, int nb) {
    __shared__ int t[512];
    int v = (threadIdx.x < nb) ? bsum[threadIdx.x] : 0;
    t[threadIdx.x] = v;
    __syncthreads();
    for (int o = 1; o < 512; o <<= 1) {
        int x = (threadIdx.x >= o) ? t[threadIdx.x - o] : 0;
        __syncthreads();
        t[threadIdx.x] += x;
        __syncthreads();
    }
    if (threadIdx.x < nb) bsum[threadIdx.x] = t[threadIdx.x] - v;
}

__global__ __launch_bounds__(256) void scan_add_rdeg(int* __restrict__ off,
                                                     const int* __restrict__ bsum,
                                                     const int* __restrict__ cnt,
                                                     float* __restrict__ rdeg, int N) {
    int i = blockIdx.x * 256 + threadIdx.x;
    if (i >= N) return;
    off[i] += bsum[blockIdx.x];
    rdeg[i] = 1.0f / fmaxf((float)cnt[i], 1.0f);
}

// pass 2: atomic-free fill; thread 0 also inits the encoded min/max accumulators
__global__ __launch_bounds__(256) void fill_kernel(const int* __restrict__ src,
                                                   const int* __restrict__ dst,
                                                   const int* __restrict__ off,
                                                   const ushort* __restrict__ rel,
                                                   int* __restrict__ srcS,
                                                   uint* __restrict__ mmfe, int E) {
    if (blockIdx.x == 0 && threadIdx.x == 0) {
        mmfe[0] = 0xFFFFFFFFu;   // running min (encoded), atomicMin
        mmfe[1] = 0u;            // running max (encoded), atomicMax
    }
    int e = blockIdx.x * 256 + threadIdx.x;
    if (e >= E) return;
    srcS[off[dst[e]] + (int)rel[e]] = src[e];
}

// ---------------- aggregate (gather, rounded-up unroll 8, no serial tail) ----------------
// wave per node, lane = feature pair; indices wave-uniform (scalar loads).
// msgb stores are non-temporal: msgb is only ever streamed by sage_mfma, and its
// 25.6 MB of allocations would evict the gather working set (the xb/h1b rows).
__global__ __launch_bounds__(256) void agg_gather(const uint* __restrict__ hb,
                                                  const int* __restrict__ off,
                                                  const int* __restrict__ srcS,
                                                  const float* __restrict__ rdeg,
                                                  uint* __restrict__ msgb, int N, int E) {
    int node = blockIdx.x * 4 + (threadIdx.x >> 6);
    int lane = threadIdx.x & 63;
    if (node >= N) return;
    int p = off[node];
    int pe = (node == N - 1) ? E : off[node + 1];
    float2 acc = make_float2(0.f, 0.f);
    if (p < pe) {
        int deg = pe - p;
        int last = pe - 1;
        for (; p < pe; p += 8) {
            int i0 = min(p + 0, last), i1 = min(p + 1, last);
            int i2 = min(p + 2, last), i3 = min(p + 3, last);
            int i4 = min(p + 4, last), i5 = min(p + 5, last);
            int i6 = min(p + 6, last), i7 = min(p + 7, last);
            int s0 = srcS[i0], s1 = srcS[i1], s2 = srcS[i2], s3 = srcS[i3];
            int s4 = srcS[i4], s5 = srcS[i5], s6 = srcS[i6], s7 = srcS[i7];
            float2 f0 = bf2f(hb[(size_t)s0 * 64 + lane]);
            float2 f1 = bf2f(hb[(size_t)s1 * 64 + lane]);
            float2 f2 = bf2f(hb[(size_t)s2 * 64 + lane]);
            float2 f3 = bf2f(hb[(size_t)s3 * 64 + lane]);
            float2 f4 = bf2f(hb[(size_t)s4 * 64 + lane]);
            float2 f5 = bf2f(hb[(size_t)s5 * 64 + lane]);
            float2 f6 = bf2f(hb[(size_t)s6 * 64 + lane]);
            float2 f7 = bf2f(hb[(size_t)s7 * 64 + lane]);
            acc.x += ((f0.x + f1.x) + (f2.x + f3.x)) + ((f4.x + f5.x) + (f6.x + f7.x));
            acc.y += ((f0.y + f1.y) + (f2.y + f3.y)) + ((f4.y + f5.y) + (f6.y + f7.y));
        }
        int d = (8 - (deg & 7)) & 7;          // duplicate count of row[last]
        if (d) {
            float2 fl = bf2f(hb[(size_t)srcS[last] * 64 + lane]);
            float fd = (float)d;
            acc.x -= fd * fl.x;
            acc.y -= fd * fl.y;
        }
    }
    float rd = rdeg[node];
    uint w = (uint)f2bf(acc.x * rd) | ((uint)f2bf(acc.y * rd) << 16);
    __builtin_nontemporal_store(w, msgb + (size_t)node * 64 + lane);
}

// ---------------- SAGE layer via MFMA (frag-major weights) ----------------
// mb (msgb) loads are non-temporal: single-use stream; keeps this layer's OUTPUT
// (the next gather target) and hb resident in L2 instead.
__global__ __launch_bounds__(256) void sage_mfma(const uint* __restrict__ hb,
                                                 const uint* __restrict__ mb,
                                                 const uint* __restrict__ Wt,  // frag-major
                                                 const float* __restrict__ bias,
                                                 ushort* __restrict__ outb, int N) {
    int wave = threadIdx.x >> 6, lane = threadIdx.x & 63;
    int m = lane & 15, q = lane >> 4;
    int r0 = blockIdx.x * 64 + wave * 16;
    int arow = r0 + m;
    if (arow >= N) arow = N - 1;

    f32x4 acc[8];
#pragma unroll
    for (int t = 0; t < 8; t++) acc[t] = (f32x4){0.f, 0.f, 0.f, 0.f};

    const uint* hrow = hb + (size_t)arow * 64;
    const uint* mrow = mb + (size_t)arow * 64;
#pragma unroll
    for (int sel = 0; sel < 2; sel++) {
        const uint* wsel = Wt + sel * 8192;
#pragma unroll
        for (int kk = 0; kk < 4; kk++) {
            int ko = kk * 16 + q * 4;
            short8 a = sel ? __builtin_nontemporal_load((const short8*)(mrow + ko))
                           : *(const short8*)(hrow + ko);
#pragma unroll
            for (int t = 0; t < 8; t++) {
                short8 b = *(const short8*)(wsel + (size_t)((kk * 8 + t) * 64 + lane) * 4);
                acc[t] = __builtin_amdgcn_mfma_f32_16x16x32_bf16(a, b, acc[t], 0, 0, 0);
            }
        }
    }

#pragma unroll
    for (int t = 0; t < 8; t++) {
        float bs = bias[16 * t + m];
#pragma unroll
        for (int r = 0; r < 4; r++) {
            int orow = r0 + q * 4 + r;
            if (orow < N) outb[(size_t)orow * 128 + 16 * t + m] = f2bf(acc[t][r] + bs);
        }
    }
}

// ---------------- edge score via MFMA matrix-vector: 16 edges per batch ----------------
// per-block min/max folded into two encoded-uint global atomics (no pmm / final pass)
__global__ __launch_bounds__(256) void edge_score_mfma(const uint* __restrict__ hb,
                                                       const int* __restrict__ off,
                                                       const int* __restrict__ srcS,
                                                       float* __restrict__ sc,
                                                       uint* __restrict__ mmfe, int N, int E) {
    int node = blockIdx.x * 4 + (threadIdx.x >> 6);
    int lane = threadIdx.x & 63;
    int m = lane & 15, q = lane >> 4;
    float lmin = INFINITY, lmax = -INFINITY;

    if (node < N) {
        int p = off[node];
        int pe = (node == N - 1) ? E : off[node + 1];
        if (p < pe) {
            const uint* nrow = hb + (size_t)node * 64;
            short8 bfr[4];
#pragma unroll
            for (int kk = 0; kk < 4; kk++)
                bfr[kk] = *(const short8*)(nrow + kk * 16 + q * 4);   // B[k][n]=h_node[k] ∀n

            for (; p < pe; p += 16) {
                int idx = p + m;
                if (idx >= pe) idx = pe - 1;                  // clamp: dup rows, stores masked
                const uint* arow = hb + (size_t)srcS[idx] * 64;
                f32x4 acc = (f32x4){0.f, 0.f, 0.f, 0.f};
#pragma unroll
                for (int kk = 0; kk < 4; kk++) {
                    short8 a = *(const short8*)(arow + kk * 16 + q * 4);
                    acc = __builtin_amdgcn_mfma_f32_16x16x32_bf16(a, bfr[kk], acc, 0, 0, 0);
                }
                // D: col=lane&15, row=q*4+r (cols identical) -> col-0 lanes own edges q*4..q*4+3
                if (m == 0) {
                    if (p + 16 <= pe) {
                        *(float4*)(sc + p + q * 4) = make_float4(acc[0], acc[1], acc[2], acc[3]);
                        float mn = fminf(fminf(acc[0], acc[1]), fminf(acc[2], acc[3]));
                        float mx = fmaxf(fmaxf(acc[0], acc[1]), fmaxf(acc[2], acc[3]));
                        lmin = fminf(lmin, mn);
                        lmax = fmaxf(lmax, mx);
                    } else {
#pragma unroll
                        for (int r = 0; r < 4; r++) {
                            int e = p + q * 4 + r;
                            if (e < pe) {
                                sc[e] = acc[r];
                                lmin = fminf(lmin, acc[r]);
                                lmax = fmaxf(lmax, acc[r]);
                            }
                        }
                    }
                }
            }
        }
    }

#pragma unroll
    for (int o = 1; o <= 32; o <<= 1) {
        lmin = fminf(lmin, __shfl_xor(lmin, o));
        lmax = fmaxf(lmax, __shfl_xor(lmax, o));
    }
    __shared__ float smin[4], smax[4];
    int wv = threadIdx.x >> 6;
    if (lane == 0) { smin[wv] = lmin; smax[wv] = lmax; }
    __syncthreads();
    if (threadIdx.x == 0) {
        float mA = fminf(fminf(smin[0], smin[1]), fminf(smin[2], smin[3]));
        float MA = fmaxf(fmaxf(smax[0], smax[1]), fmaxf(smax[2], smax[3]));
        atomicMin(&mmfe[0], fenc(mA));
        atomicMax(&mmfe[1], fenc(MA));
    }
}

// out[e] = (sc[off[dst[e]] + rel[e]] - mn) * inv
__global__ __launch_bounds__(256) void norm_kernel(const float* __restrict__ sc,
                                                   const int* __restrict__ dst,
                                                   const ushort* __restrict__ rel,
                                                   const int* __restrict__ off,
                                                   float* __restrict__ out,
                                                   const uint* __restrict__ mmfe, int E) {
    float mn = fdec(mmfe[0]);
    float mx = fdec(mmfe[1]);
    float inv = 1.0f / (mx - mn);
    int i = blockIdx.x * 256 + threadIdx.x;
    if (i < E) {
        int p = off[dst[i]] + (int)rel[i];
        out[i] = (sc[p] - mn) * inv;
    }
}

extern "C" void kernel_launch(void* const* d_in, const int* in_sizes, int n_in,
                              void* d_out, int out_size, void* d_ws, size_t ws_size,
                              hipStream_t stream) {
    const float* x   = (const float*)d_in[0];
    const int*   src = (const int*)d_in[1];
    const int*   dst = (const int*)d_in[2];
    const float* Ws1 = (const float*)d_in[3];
    const float* Wn1 = (const float*)d_in[4];
    const float* b1  = (const float*)d_in[5];
    const float* Ws2 = (const float*)d_in[6];
    const float* Wn2 = (const float*)d_in[7];
    const float* b2  = (const float*)d_in[8];

    int N = in_sizes[0] / F;   // 100000
    int E = in_sizes[1];       // 1600000
    float* out = (float*)d_out;

    int nbN = (N + 255) / 256;
    int nbE = (E + 255) / 256;
    int nbEdgeBlocks = (N + 3) / 4;       // 25000
    int NF4 = N * F / 4;

    // workspace layout (4-byte elements)
    int* off  = (int*)d_ws;                  // N
    int* cnt  = off + N;                     // N
    int* srcS = cnt + N;                     // E
    ushort* rel = (ushort*)(srcS + E);       // E ushorts = E/2 words
    float* sc = (float*)((int*)rel + E / 2); // E
    int* bsum = (int*)(sc + E);              // 1024
    float* rdeg = (float*)(bsum + 1024);     // N
    uint* mmfe = (uint*)(rdeg + N);          // 2 (+2 pad) encoded min/max
    float2* pmm = (float2*)(mmfe + 4);       // 25600 float2 (unused, layout kept)
    uint* Wtb = (uint*)(pmm + 25600);        // 32768 uints (frag-major)
    size_t elemOff = 3 * (size_t)N + 2 * (size_t)E + (size_t)E / 2 + 1024 + 4 + 51200 + 32768;
    elemOff = (elemOff + 3) & ~(size_t)3;    // 16B align
    uint* xb   = (uint*)d_ws + elemOff;      // N*64
    uint* msgb = xb + (size_t)N * 64;        // N*64
    uint* h1b  = msgb + (size_t)N * 64;      // N*64
    uint* h2b  = h1b + (size_t)N * 64;       // N*64

    // init
    (void)hipMemsetAsync(cnt, 0, (size_t)N * sizeof(int), stream);

    // CSR rank + prep fused (independent work), then scan + atomic-free fill
    int nbPrep = (NF4 + 4 * 16384 + 255) / 256;
    rank_prep<<<nbE + nbPrep, 256, 0, stream>>>(dst, cnt, rel, E, nbE,
                                                x, Ws1, Wn1, Ws2, Wn2, xb, (ushort*)Wtb, NF4);
    scan_block<<<nbN, 256, 0, stream>>>(cnt, off, bsum, N);
    scan_sums<<<1, 512, 0, stream>>>(bsum, nbN);
    scan_add_rdeg<<<nbN, 256, 0, stream>>>(off, bsum, cnt, rdeg, N);
    fill_kernel<<<nbE, 256, 0, stream>>>(src, dst, off, rel, srcS, mmfe, E);

    // layer 1
    agg_gather<<<(N + 3) / 4, 256, 0, stream>>>(xb, off, srcS, rdeg, msgb, N, E);
    sage_mfma<<<(N + 63) / 64, 256, 0, stream>>>(xb, msgb, Wtb, b1, (ushort*)h1b, N);

    // layer 2
    agg_gather<<<(N + 3) / 4, 256, 0, stream>>>(h1b, off, srcS, rdeg, msgb, N, E);
    sage_mfma<<<(N + 63) / 64, 256, 0, stream>>>(h1b, msgb, Wtb + 16384, b2, (ushort*)h2b, N);

    // edge scores via MFMA (CSR order), min/max via encoded atomics, then normalize
    edge_score_mfma<<<nbEdgeBlocks, 256, 0, stream>>>(h2b, off, srcS, sc, mmfe, N, E);
    norm_kernel<<<(E + 255) / 256, 256, 0, stream>>>(sc, dst, rel, off, out, mmfe, E);
}

// Round 8
// 579.306 us; speedup vs baseline: 1.7969x; 1.7969x over previous
//
#include <hip/hip_runtime.h>
#include <hip/hip_bf16.h>

#define F 128

typedef unsigned int uint;
typedef unsigned short ushort;
typedef __attribute__((ext_vector_type(8))) short short8;   // 8 bf16
typedef __attribute__((ext_vector_type(4))) float f32x4;
typedef __attribute__((ext_vector_type(4))) uint uint4v;    // native vector for nt-load

__device__ inline ushort f2bf(float f) {
    uint u = __float_as_uint(f);
    u += 0x7FFF + ((u >> 16) & 1);   // round-to-nearest-even
    return (ushort)(u >> 16);
}
__device__ inline float2 bf2f(uint u) {
    return make_float2(__uint_as_float(u << 16), __uint_as_float(u & 0xFFFF0000u));
}

// ---------------- CSR build ----------------
// fused: blocks [0,nbE) do rank (histogram + per-edge rank, one atomic pass);
// blocks [nbE, ...) do prep (x cast + weight frag-major swizzle).
__global__ __launch_bounds__(256) void rank_prep(const int* __restrict__ dst,
                                                 int* __restrict__ cnt,
                                                 ushort* __restrict__ rel, int E, int nbE,
                                                 const float* __restrict__ x,
                                                 const float* __restrict__ W0,
                                                 const float* __restrict__ W1,
                                                 const float* __restrict__ W2,
                                                 const float* __restrict__ W3,
                                                 uint* __restrict__ xb,
                                                 ushort* __restrict__ Wt, int NF4) {
    int b = blockIdx.x;
    if (b < nbE) {
        int e = b * 256 + threadIdx.x;
        if (e < E) rel[e] = (ushort)atomicAdd(&cnt[dst[e]], 1);
        return;
    }
    int i = (b - nbE) * 256 + threadIdx.x;
    if (i < NF4) {
        // non-temporal: x is read once; don't evict the xb gather target from L2
        uint4v u = __builtin_nontemporal_load(((const uint4v*)x) + i);
        uint ua = (uint)f2bf(__uint_as_float(u.x)) | ((uint)f2bf(__uint_as_float(u.y)) << 16);
        uint ub = (uint)f2bf(__uint_as_float(u.z)) | ((uint)f2bf(__uint_as_float(u.w)) << 16);
        ((uint2*)xb)[i] = make_uint2(ua, ub);
    } else {
        int idx = i - NF4;
        if (idx >= 4 * 16384) return;
        int j    = idx & 7;
        int lane = (idx >> 3) & 63;
        int t    = (idx >> 9) & 7;
        int kk   = (idx >> 12) & 3;
        int mat  = idx >> 14;
        int n = 16 * t + (lane & 15);
        int k = 32 * kk + 8 * (lane >> 4) + j;
        const float* W = (mat == 0) ? W0 : (mat == 1) ? W1 : (mat == 2) ? W2 : W3;
        Wt[idx] = f2bf(W[k * 128 + n]);
    }
}

__global__ __launch_bounds__(256) void scan_block(const int* __restrict__ cnt,
                                                  int* __restrict__ off,
                                                  int* __restrict__ bsum, int N) {
    __shared__ int t[256];
    int i = blockIdx.x * 256 + threadIdx.x;
    int v = (i < N) ? cnt[i] : 0;
    t[threadIdx.x] = v;
    __syncthreads();
    for (int o = 1; o < 256; o <<= 1) {
        int x = (threadIdx.x >= o) ? t[threadIdx.x - o] : 0;
        __syncthreads();
        t[threadIdx.x] += x;
        __syncthreads();
    }
    if (i < N) off[i] = t[threadIdx.x] - v;
    if (threadIdx.x == 255) bsum[blockIdx.x] = t[255];
}

__global__ __launch_bounds__(512) void scan_sums(int* __restrict__ bsum, int nb) {
    __shared__ int t[512];
    int v = (threadIdx.x < nb) ? bsum[threadIdx.x] : 0;
    t[threadIdx.x] = v;
    __syncthreads();
    for (int o = 1; o < 512; o <<= 1) {
        int x = (threadIdx.x >= o) ? t[threadIdx.x - o] : 0;
        __syncthreads();
        t[threadIdx.x] += x;
        __syncthreads();
    }
    if (threadIdx.x < nb) bsum[threadIdx.x] = t[threadIdx.x] - v;
}

__global__ __launch_bounds__(256) void scan_add_rdeg(int* __restrict__ off,
                                                     const int* __restrict__ bsum,
                                                     const int* __restrict__ cnt,
                                                     float* __restrict__ rdeg, int N) {
    int i = blockIdx.x * 256 + threadIdx.x;
    if (i >= N) return;
    off[i] += bsum[blockIdx.x];
    rdeg[i] = 1.0f / fmaxf((float)cnt[i], 1.0f);
}

__global__ __launch_bounds__(256) void fill_kernel(const int* __restrict__ src,
                                                   const int* __restrict__ dst,
                                                   const int* __restrict__ off,
                                                   const ushort* __restrict__ rel,
                                                   int* __restrict__ srcS, int E) {
    int e = blockIdx.x * 256 + threadIdx.x;
    if (e >= E) return;
    srcS[off[dst[e]] + (int)rel[e]] = src[e];
}

// ---------------- fused SAGE layer: aggregate (LDS-staged) + MFMA ----------------
// Each wave aggregates the 16 node rows it will feed its own MFMAs, staging bf16 msg
// rows in LDS. No cross-wave sharing -> no barrier; waves drift, overlapping gather
// with MFMA. LDS XOR-swizzle (col ^ ((row&15)<<2)) makes the per-lane b128 A-reads
// uniform across the 8 4-bank windows (conflict-free) and the writes a permutation.
// Eliminates the msgb global roundtrip (2x25.6 MB/layer) and the bf16 repack.
__global__ __launch_bounds__(256) void sage_fused(const uint* __restrict__ hb,
                                                  const int* __restrict__ off,
                                                  const int* __restrict__ srcS,
                                                  const float* __restrict__ rdeg,
                                                  const uint* __restrict__ Wt,  // frag-major
                                                  const float* __restrict__ bias,
                                                  ushort* __restrict__ outb, int N, int E) {
    __shared__ uint lmsg[64][64];
    int wave = threadIdx.x >> 6, lane = threadIdx.x & 63;

    // ---- phase 1: aggregate this wave's 16 rows (wave-per-node, lane = feature pair) ----
#pragma unroll 1
    for (int i = 0; i < 16; ++i) {
        int lr = wave * 16 + i;
        int node = blockIdx.x * 64 + lr;
        if (node > N - 1) node = N - 1;
        int p = off[node];
        int pe = (node == N - 1) ? E : off[node + 1];
        float2 acc = make_float2(0.f, 0.f);
        if (p < pe) {
            int deg = pe - p;
            int last = pe - 1;
            for (; p < pe; p += 8) {
                int i0 = min(p + 0, last), i1 = min(p + 1, last);
                int i2 = min(p + 2, last), i3 = min(p + 3, last);
                int i4 = min(p + 4, last), i5 = min(p + 5, last);
                int i6 = min(p + 6, last), i7 = min(p + 7, last);
                int s0 = srcS[i0], s1 = srcS[i1], s2 = srcS[i2], s3 = srcS[i3];
                int s4 = srcS[i4], s5 = srcS[i5], s6 = srcS[i6], s7 = srcS[i7];
                float2 f0 = bf2f(hb[(size_t)s0 * 64 + lane]);
                float2 f1 = bf2f(hb[(size_t)s1 * 64 + lane]);
                float2 f2 = bf2f(hb[(size_t)s2 * 64 + lane]);
                float2 f3 = bf2f(hb[(size_t)s3 * 64 + lane]);
                float2 f4 = bf2f(hb[(size_t)s4 * 64 + lane]);
                float2 f5 = bf2f(hb[(size_t)s5 * 64 + lane]);
                float2 f6 = bf2f(hb[(size_t)s6 * 64 + lane]);
                float2 f7 = bf2f(hb[(size_t)s7 * 64 + lane]);
                acc.x += ((f0.x + f1.x) + (f2.x + f3.x)) + ((f4.x + f5.x) + (f6.x + f7.x));
                acc.y += ((f0.y + f1.y) + (f2.y + f3.y)) + ((f4.y + f5.y) + (f6.y + f7.y));
            }
            int d = (8 - (deg & 7)) & 7;      // duplicate count of row[last]
            if (d) {
                float2 fl = bf2f(hb[(size_t)srcS[last] * 64 + lane]);
                float fd = (float)d;
                acc.x -= fd * fl.x;
                acc.y -= fd * fl.y;
            }
        }
        float rd = rdeg[node];
        lmsg[lr][lane ^ ((lr & 15) << 2)] =
            (uint)f2bf(acc.x * rd) | ((uint)f2bf(acc.y * rd) << 16);
    }

    // ---- phase 2: MFMA (self rows from global, msg rows from LDS) ----
    int m = lane & 15, q = lane >> 4;
    int r0 = blockIdx.x * 64 + wave * 16;
    int arow = r0 + m;
    if (arow >= N) arow = N - 1;
    const uint* hrow = hb + (size_t)arow * 64;
    int lrm = wave * 16 + m;

    f32x4 acc[8];
#pragma unroll
    for (int t = 0; t < 8; t++) acc[t] = (f32x4){0.f, 0.f, 0.f, 0.f};

#pragma unroll
    for (int sel = 0; sel < 2; sel++) {
        const uint* wsel = Wt + sel * 8192;
#pragma unroll
        for (int kk = 0; kk < 4; kk++) {
            int ko = kk * 16 + q * 4;
            short8 a = sel ? *(const short8*)&lmsg[lrm][ko ^ (m << 2)]
                           : *(const short8*)(hrow + ko);
#pragma unroll
            for (int t = 0; t < 8; t++) {
                short8 b = *(const short8*)(wsel + (size_t)((kk * 8 + t) * 64 + lane) * 4);
                acc[t] = __builtin_amdgcn_mfma_f32_16x16x32_bf16(a, b, acc[t], 0, 0, 0);
            }
        }
    }

#pragma unroll
    for (int t = 0; t < 8; t++) {
        float bs = bias[16 * t + m];
#pragma unroll
        for (int r = 0; r < 4; r++) {
            int orow = r0 + q * 4 + r;
            if (orow < N) outb[(size_t)orow * 128 + 16 * t + m] = f2bf(acc[t][r] + bs);
        }
    }
}

// ---------------- edge score via MFMA matrix-vector: 16 edges per batch ----------------
__global__ __launch_bounds__(256) void edge_score_mfma(const uint* __restrict__ hb,
                                                       const int* __restrict__ off,
                                                       const int* __restrict__ srcS,
                                                       float* __restrict__ sc,
                                                       float2* __restrict__ pmm, int N, int E) {
    int node = blockIdx.x * 4 + (threadIdx.x >> 6);
    int lane = threadIdx.x & 63;
    int m = lane & 15, q = lane >> 4;
    float lmin = INFINITY, lmax = -INFINITY;

    if (node < N) {
        int p = off[node];
        int pe = (node == N - 1) ? E : off[node + 1];
        if (p < pe) {
            const uint* nrow = hb + (size_t)node * 64;
            short8 bfr[4];
#pragma unroll
            for (int kk = 0; kk < 4; kk++)
                bfr[kk] = *(const short8*)(nrow + kk * 16 + q * 4);   // B[k][n]=h_node[k] ∀n

            for (; p < pe; p += 16) {
                int idx = p + m;
                if (idx >= pe) idx = pe - 1;                  // clamp: dup rows, stores masked
                const uint* arow = hb + (size_t)srcS[idx] * 64;
                f32x4 acc = (f32x4){0.f, 0.f, 0.f, 0.f};
#pragma unroll
                for (int kk = 0; kk < 4; kk++) {
                    short8 a = *(const short8*)(arow + kk * 16 + q * 4);
                    acc = __builtin_amdgcn_mfma_f32_16x16x32_bf16(a, bfr[kk], acc, 0, 0, 0);
                }
                // D: col=lane&15, row=q*4+r (cols identical) -> col-0 lanes own edges q*4..q*4+3
                if (m == 0) {
                    if (p + 16 <= pe) {
                        *(float4*)(sc + p + q * 4) = make_float4(acc[0], acc[1], acc[2], acc[3]);
                        float mn = fminf(fminf(acc[0], acc[1]), fminf(acc[2], acc[3]));
                        float mx = fmaxf(fmaxf(acc[0], acc[1]), fmaxf(acc[2], acc[3]));
                        lmin = fminf(lmin, mn);
                        lmax = fmaxf(lmax, mx);
                    } else {
#pragma unroll
                        for (int r = 0; r < 4; r++) {
                            int e = p + q * 4 + r;
                            if (e < pe) {
                                sc[e] = acc[r];
                                lmin = fminf(lmin, acc[r]);
                                lmax = fmaxf(lmax, acc[r]);
                            }
                        }
                    }
                }
            }
        }
    }

#pragma unroll
    for (int o = 1; o <= 32; o <<= 1) {
        lmin = fminf(lmin, __shfl_xor(lmin, o));
        lmax = fmaxf(lmax, __shfl_xor(lmax, o));
    }
    __shared__ float smin[4], smax[4];
    int wv = threadIdx.x >> 6;
    if (lane == 0) { smin[wv] = lmin; smax[wv] = lmax; }
    __syncthreads();
    if (threadIdx.x == 0) {
        float mA = fminf(fminf(smin[0], smin[1]), fminf(smin[2], smin[3]));
        float MA = fmaxf(fmaxf(smax[0], smax[1]), fmaxf(smax[2], smax[3]));
        pmm[blockIdx.x] = make_float2(mA, MA);
    }
}

__global__ __launch_bounds__(1024) void minmax_final(const float2* __restrict__ pmm,
                                                     float* __restrict__ mmf, int nb) {
    float vmin = INFINITY, vmax = -INFINITY;
    for (int i = threadIdx.x; i < nb; i += 1024) {
        float2 v = pmm[i];
        vmin = fminf(vmin, v.x);
        vmax = fmaxf(vmax, v.y);
    }
#pragma unroll
    for (int o = 1; o <= 32; o <<= 1) {
        vmin = fminf(vmin, __shfl_xor(vmin, o));
        vmax = fmaxf(vmax, __shfl_xor(vmax, o));
    }
    __shared__ float smin[16], smax[16];
    int lane = threadIdx.x & 63, wv = threadIdx.x >> 6;
    if (lane == 0) { smin[wv] = vmin; smax[wv] = vmax; }
    __syncthreads();
    if (threadIdx.x == 0) {
        float m = smin[0], M = smax[0];
        for (int w = 1; w < 16; w++) { m = fminf(m, smin[w]); M = fmaxf(M, smax[w]); }
        mmf[0] = m;
        mmf[1] = M;
    }
}

// out[e] = (sc[off[dst[e]] + rel[e]] - mn) * inv
__global__ __launch_bounds__(256) void norm_kernel(const float* __restrict__ sc,
                                                   const int* __restrict__ dst,
                                                   const ushort* __restrict__ rel,
                                                   const int* __restrict__ off,
                                                   float* __restrict__ out,
                                                   const float* __restrict__ mmf, int E) {
    float mn = mmf[0];
    float mx = mmf[1];
    float inv = 1.0f / (mx - mn);
    int i = blockIdx.x * 256 + threadIdx.x;
    if (i < E) {
        int p = off[dst[i]] + (int)rel[i];
        out[i] = (sc[p] - mn) * inv;
    }
}

extern "C" void kernel_launch(void* const* d_in, const int* in_sizes, int n_in,
                              void* d_out, int out_size, void* d_ws, size_t ws_size,
                              hipStream_t stream) {
    const float* x   = (const float*)d_in[0];
    const int*   src = (const int*)d_in[1];
    const int*   dst = (const int*)d_in[2];
    const float* Ws1 = (const float*)d_in[3];
    const float* Wn1 = (const float*)d_in[4];
    const float* b1  = (const float*)d_in[5];
    const float* Ws2 = (const float*)d_in[6];
    const float* Wn2 = (const float*)d_in[7];
    const float* b2  = (const float*)d_in[8];

    int N = in_sizes[0] / F;   // 100000
    int E = in_sizes[1];       // 1600000
    float* out = (float*)d_out;

    int nbN = (N + 255) / 256;
    int nbE = (E + 255) / 256;
    int nbEdgeBlocks = (N + 3) / 4;       // 25000
    int NF4 = N * F / 4;

    // workspace layout (4-byte elements)
    int* off  = (int*)d_ws;                  // N
    int* cnt  = off + N;                     // N
    int* srcS = cnt + N;                     // E
    ushort* rel = (ushort*)(srcS + E);       // E ushorts = E/2 words
    float* sc = (float*)((int*)rel + E / 2); // E
    int* bsum = (int*)(sc + E);              // 1024
    float* rdeg = (float*)(bsum + 1024);     // N
    float* mmf = (float*)(rdeg + N);         // 2 (+2 pad)
    float2* pmm = (float2*)(mmf + 4);        // 25600 float2
    uint* Wtb = (uint*)(pmm + 25600);        // 32768 uints (frag-major)
    size_t elemOff = 3 * (size_t)N + 2 * (size_t)E + (size_t)E / 2 + 1024 + 4 + 51200 + 32768;
    elemOff = (elemOff + 3) & ~(size_t)3;    // 16B align
    uint* xb   = (uint*)d_ws + elemOff;      // N*64
    uint* h1b  = xb + (size_t)N * 64;        // N*64
    uint* h2b  = h1b + (size_t)N * 64;       // N*64

    // init
    (void)hipMemsetAsync(cnt, 0, (size_t)N * sizeof(int), stream);

    // CSR rank + prep fused (independent work), then scan + atomic-free fill
    int nbPrep = (NF4 + 4 * 16384 + 255) / 256;
    rank_prep<<<nbE + nbPrep, 256, 0, stream>>>(dst, cnt, rel, E, nbE,
                                                x, Ws1, Wn1, Ws2, Wn2, xb, (ushort*)Wtb, NF4);
    scan_block<<<nbN, 256, 0, stream>>>(cnt, off, bsum, N);
    scan_sums<<<1, 512, 0, stream>>>(bsum, nbN);
    scan_add_rdeg<<<nbN, 256, 0, stream>>>(off, bsum, cnt, rdeg, N);
    fill_kernel<<<nbE, 256, 0, stream>>>(src, dst, off, rel, srcS, E);

    // fused layers: aggregate (LDS) + MFMA in one kernel each
    int nbSage = (N + 63) / 64;
    sage_fused<<<nbSage, 256, 0, stream>>>(xb, off, srcS, rdeg, Wtb, b1, (ushort*)h1b, N, E);
    sage_fused<<<nbSage, 256, 0, stream>>>(h1b, off, srcS, rdeg, Wtb + 16384, b2,
                                           (ushort*)h2b, N, E);

    // edge scores via MFMA (CSR order + per-block partials) + final reduce + normalize
    edge_score_mfma<<<nbEdgeBlocks, 256, 0, stream>>>(h2b, off, srcS, sc, pmm, N, E);
    minmax_final<<<1, 1024, 0, stream>>>(pmm, mmf, nbEdgeBlocks);
    norm_kernel<<<(E + 255) / 256, 256, 0, stream>>>(sc, dst, rel, off, out, mmf, E);
}

// Round 9
// 543.748 us; speedup vs baseline: 1.9144x; 1.0654x over previous
//
#include <hip/hip_runtime.h>
#include <hip/hip_bf16.h>

#define F 128

typedef unsigned int uint;
typedef unsigned short ushort;
typedef __attribute__((ext_vector_type(8))) short short8;   // 8 bf16
typedef __attribute__((ext_vector_type(4))) float f32x4;
typedef __attribute__((ext_vector_type(4))) uint uint4v;    // native vector for nt-load

__device__ inline ushort f2bf(float f) {
    uint u = __float_as_uint(f);
    u += 0x7FFF + ((u >> 16) & 1);   // round-to-nearest-even
    return (ushort)(u >> 16);
}
__device__ inline float2 bf2f(uint u) {
    return make_float2(__uint_as_float(u << 16), __uint_as_float(u & 0xFFFF0000u));
}

// ---------------- CSR build ----------------
// fused: blocks [0,nbE) do rank (histogram + per-edge rank, one atomic pass);
// blocks [nbE, ...) do prep (x cast + weight frag-major swizzle).
__global__ __launch_bounds__(256) void rank_prep(const int* __restrict__ dst,
                                                 int* __restrict__ cnt,
                                                 ushort* __restrict__ rel, int E, int nbE,
                                                 const float* __restrict__ x,
                                                 const float* __restrict__ W0,
                                                 const float* __restrict__ W1,
                                                 const float* __restrict__ W2,
                                                 const float* __restrict__ W3,
                                                 uint* __restrict__ xb,
                                                 ushort* __restrict__ Wt, int NF4) {
    int b = blockIdx.x;
    if (b < nbE) {
        int e = b * 256 + threadIdx.x;
        if (e < E) rel[e] = (ushort)atomicAdd(&cnt[dst[e]], 1);
        return;
    }
    int i = (b - nbE) * 256 + threadIdx.x;
    if (i < NF4) {
        // non-temporal: x is read once; don't evict the xb gather target from L2
        uint4v u = __builtin_nontemporal_load(((const uint4v*)x) + i);
        uint ua = (uint)f2bf(__uint_as_float(u.x)) | ((uint)f2bf(__uint_as_float(u.y)) << 16);
        uint ub = (uint)f2bf(__uint_as_float(u.z)) | ((uint)f2bf(__uint_as_float(u.w)) << 16);
        ((uint2*)xb)[i] = make_uint2(ua, ub);
    } else {
        int idx = i - NF4;
        if (idx >= 4 * 16384) return;
        int j    = idx & 7;
        int lane = (idx >> 3) & 63;
        int t    = (idx >> 9) & 7;
        int kk   = (idx >> 12) & 3;
        int mat  = idx >> 14;
        int n = 16 * t + (lane & 15);
        int k = 32 * kk + 8 * (lane >> 4) + j;
        const float* W = (mat == 0) ? W0 : (mat == 1) ? W1 : (mat == 2) ? W2 : W3;
        Wt[idx] = f2bf(W[k * 128 + n]);
    }
}

__global__ __launch_bounds__(256) void scan_block(const int* __restrict__ cnt,
                                                  int* __restrict__ off,
                                                  int* __restrict__ bsum, int N) {
    __shared__ int t[256];
    int i = blockIdx.x * 256 + threadIdx.x;
    int v = (i < N) ? cnt[i] : 0;
    t[threadIdx.x] = v;
    __syncthreads();
    for (int o = 1; o < 256; o <<= 1) {
        int x = (threadIdx.x >= o) ? t[threadIdx.x - o] : 0;
        __syncthreads();
        t[threadIdx.x] += x;
        __syncthreads();
    }
    if (i < N) off[i] = t[threadIdx.x] - v;
    if (threadIdx.x == 255) bsum[blockIdx.x] = t[255];
}

__global__ __launch_bounds__(512) void scan_sums(int* __restrict__ bsum, int nb) {
    __shared__ int t[512];
    int v = (threadIdx.x < nb) ? bsum[threadIdx.x] : 0;
    t[threadIdx.x] = v;
    __syncthreads();
    for (int o = 1; o < 512; o <<= 1) {
        int x = (threadIdx.x >= o) ? t[threadIdx.x - o] : 0;
        __syncthreads();
        t[threadIdx.x] += x;
        __syncthreads();
    }
    if (threadIdx.x < nb) bsum[threadIdx.x] = t[threadIdx.x] - v;
}

__global__ __launch_bounds__(256) void scan_add_rdeg(int* __restrict__ off,
                                                     const int* __restrict__ bsum,
                                                     const int* __restrict__ cnt,
                                                     float* __restrict__ rdeg, int N) {
    int i = blockIdx.x * 256 + threadIdx.x;
    if (i >= N) return;
    off[i] += bsum[blockIdx.x];
    rdeg[i] = 1.0f / fmaxf((float)cnt[i], 1.0f);
}

__global__ __launch_bounds__(256) void fill_kernel(const int* __restrict__ src,
                                                   const int* __restrict__ dst,
                                                   const int* __restrict__ off,
                                                   const ushort* __restrict__ rel,
                                                   int* __restrict__ srcS, int E) {
    int e = blockIdx.x * 256 + threadIdx.x;
    if (e >= E) return;
    srcS[off[dst[e]] + (int)rel[e]] = src[e];
}

// ---------------- aggregate (gather, rounded-up unroll 16) ----------------
// wave per node, lane = feature pair; indices wave-uniform (scalar loads).
// Unroll 16 (was 8): doubles outstanding gathers per wave to test whether the
// 3.4 TB/s fetch plateau is concurrency-limited or the random-line HBM ceiling.
// Duplicate adds of row[last] (up to 15) subtracted afterwards.
__global__ __launch_bounds__(256) void agg_gather(const uint* __restrict__ hb,
                                                  const int* __restrict__ off,
                                                  const int* __restrict__ srcS,
                                                  const float* __restrict__ rdeg,
                                                  uint* __restrict__ msgb, int N, int E) {
    int node = blockIdx.x * 4 + (threadIdx.x >> 6);
    int lane = threadIdx.x & 63;
    if (node >= N) return;
    int p = off[node];
    int pe = (node == N - 1) ? E : off[node + 1];
    float2 acc = make_float2(0.f, 0.f);
    if (p < pe) {
        int deg = pe - p;
        int last = pe - 1;
        for (; p < pe; p += 16) {
            int s[16];
#pragma unroll
            for (int j = 0; j < 16; j++) s[j] = srcS[min(p + j, last)];
            float2 f[16];
#pragma unroll
            for (int j = 0; j < 16; j++) f[j] = bf2f(hb[(size_t)s[j] * 64 + lane]);
            float2 t0 = make_float2(0.f, 0.f), t1 = make_float2(0.f, 0.f);
#pragma unroll
            for (int j = 0; j < 8; j++) {
                t0.x += f[j].x;       t0.y += f[j].y;
                t1.x += f[j + 8].x;   t1.y += f[j + 8].y;
            }
            acc.x += t0.x + t1.x;
            acc.y += t0.y + t1.y;
        }
        int d = (16 - (deg & 15)) & 15;       // duplicate count of row[last]
        if (d) {
            float2 fl = bf2f(hb[(size_t)srcS[last] * 64 + lane]);
            float fd = (float)d;
            acc.x -= fd * fl.x;
            acc.y -= fd * fl.y;
        }
    }
    float rd = rdeg[node];
    uint w = (uint)f2bf(acc.x * rd) | ((uint)f2bf(acc.y * rd) << 16);
    __builtin_nontemporal_store(w, msgb + (size_t)node * 64 + lane);
}

// ---------------- SAGE layer via MFMA (frag-major weights) ----------------
// mb (msgb) loads non-temporal: single-use stream.
__global__ __launch_bounds__(256) void sage_mfma(const uint* __restrict__ hb,
                                                 const uint* __restrict__ mb,
                                                 const uint* __restrict__ Wt,  // frag-major
                                                 const float* __restrict__ bias,
                                                 ushort* __restrict__ outb, int N) {
    int wave = threadIdx.x >> 6, lane = threadIdx.x & 63;
    int m = lane & 15, q = lane >> 4;
    int r0 = blockIdx.x * 64 + wave * 16;
    int arow = r0 + m;
    if (arow >= N) arow = N - 1;

    f32x4 acc[8];
#pragma unroll
    for (int t = 0; t < 8; t++) acc[t] = (f32x4){0.f, 0.f, 0.f, 0.f};

    const uint* hrow = hb + (size_t)arow * 64;
    const uint* mrow = mb + (size_t)arow * 64;
#pragma unroll
    for (int sel = 0; sel < 2; sel++) {
        const uint* wsel = Wt + sel * 8192;
#pragma unroll
        for (int kk = 0; kk < 4; kk++) {
            int ko = kk * 16 + q * 4;
            short8 a = sel ? __builtin_nontemporal_load((const short8*)(mrow + ko))
                           : *(const short8*)(hrow + ko);
#pragma unroll
            for (int t = 0; t < 8; t++) {
                short8 b = *(const short8*)(wsel + (size_t)((kk * 8 + t) * 64 + lane) * 4);
                acc[t] = __builtin_amdgcn_mfma_f32_16x16x32_bf16(a, b, acc[t], 0, 0, 0);
            }
        }
    }

#pragma unroll
    for (int t = 0; t < 8; t++) {
        float bs = bias[16 * t + m];
#pragma unroll
        for (int r = 0; r < 4; r++) {
            int orow = r0 + q * 4 + r;
            if (orow < N) outb[(size_t)orow * 128 + 16 * t + m] = f2bf(acc[t][r] + bs);
        }
    }
}

// ---------------- edge score via MFMA matrix-vector: 16 edges per batch ----------------
__global__ __launch_bounds__(256) void edge_score_mfma(const uint* __restrict__ hb,
                                                       const int* __restrict__ off,
                                                       const int* __restrict__ srcS,
                                                       float* __restrict__ sc,
                                                       float2* __restrict__ pmm, int N, int E) {
    int node = blockIdx.x * 4 + (threadIdx.x >> 6);
    int lane = threadIdx.x & 63;
    int m = lane & 15, q = lane >> 4;
    float lmin = INFINITY, lmax = -INFINITY;

    if (node < N) {
        int p = off[node];
        int pe = (node == N - 1) ? E : off[node + 1];
        if (p < pe) {
            const uint* nrow = hb + (size_t)node * 64;
            short8 bfr[4];
#pragma unroll
            for (int kk = 0; kk < 4; kk++)
                bfr[kk] = *(const short8*)(nrow + kk * 16 + q * 4);   // B[k][n]=h_node[k] ∀n

            for (; p < pe; p += 16) {
                int idx = p + m;
                if (idx >= pe) idx = pe - 1;                  // clamp: dup rows, stores masked
                const uint* arow = hb + (size_t)srcS[idx] * 64;
                f32x4 acc = (f32x4){0.f, 0.f, 0.f, 0.f};
#pragma unroll
                for (int kk = 0; kk < 4; kk++) {
                    short8 a = *(const short8*)(arow + kk * 16 + q * 4);
                    acc = __builtin_amdgcn_mfma_f32_16x16x32_bf16(a, bfr[kk], acc, 0, 0, 0);
                }
                // D: col=lane&15, row=q*4+r (cols identical) -> col-0 lanes own edges q*4..q*4+3
                if (m == 0) {
                    if (p + 16 <= pe) {
                        *(float4*)(sc + p + q * 4) = make_float4(acc[0], acc[1], acc[2], acc[3]);
                        float mn = fminf(fminf(acc[0], acc[1]), fminf(acc[2], acc[3]));
                        float mx = fmaxf(fmaxf(acc[0], acc[1]), fmaxf(acc[2], acc[3]));
                        lmin = fminf(lmin, mn);
                        lmax = fmaxf(lmax, mx);
                    } else {
#pragma unroll
                        for (int r = 0; r < 4; r++) {
                            int e = p + q * 4 + r;
                            if (e < pe) {
                                sc[e] = acc[r];
                                lmin = fminf(lmin, acc[r]);
                                lmax = fmaxf(lmax, acc[r]);
                            }
                        }
                    }
                }
            }
        }
    }

#pragma unroll
    for (int o = 1; o <= 32; o <<= 1) {
        lmin = fminf(lmin, __shfl_xor(lmin, o));
        lmax = fmaxf(lmax, __shfl_xor(lmax, o));
    }
    __shared__ float smin[4], smax[4];
    int wv = threadIdx.x >> 6;
    if (lane == 0) { smin[wv] = lmin; smax[wv] = lmax; }
    __syncthreads();
    if (threadIdx.x == 0) {
        float mA = fminf(fminf(smin[0], smin[1]), fminf(smin[2], smin[3]));
        float MA = fmaxf(fmaxf(smax[0], smax[1]), fmaxf(smax[2], smax[3]));
        pmm[blockIdx.x] = make_float2(mA, MA);
    }
}

__global__ __launch_bounds__(1024) void minmax_final(const float2* __restrict__ pmm,
                                                     float* __restrict__ mmf, int nb) {
    float vmin = INFINITY, vmax = -INFINITY;
    for (int i = threadIdx.x; i < nb; i += 1024) {
        float2 v = pmm[i];
        vmin = fminf(vmin, v.x);
        vmax = fmaxf(vmax, v.y);
    }
#pragma unroll
    for (int o = 1; o <= 32; o <<= 1) {
        vmin = fminf(vmin, __shfl_xor(vmin, o));
        vmax = fmaxf(vmax, __shfl_xor(vmax, o));
    }
    __shared__ float smin[16], smax[16];
    int lane = threadIdx.x & 63, wv = threadIdx.x >> 6;
    if (lane == 0) { smin[wv] = vmin; smax[wv] = vmax; }
    __syncthreads();
    if (threadIdx.x == 0) {
        float m = smin[0], M = smax[0];
        for (int w = 1; w < 16; w++) { m = fminf(m, smin[w]); M = fmaxf(M, smax[w]); }
        mmf[0] = m;
        mmf[1] = M;
    }
}

// out[e] = (sc[off[dst[e]] + rel[e]] - mn) * inv
__global__ __launch_bounds__(256) void norm_kernel(const float* __restrict__ sc,
                                                   const int* __restrict__ dst,
                                                   const ushort* __restrict__ rel,
                                                   const int* __restrict__ off,
                                                   float* __restrict__ out,
                                                   const float* __restrict__ mmf, int E) {
    float mn = mmf[0];
    float mx = mmf[1];
    float inv = 1.0f / (mx - mn);
    int i = blockIdx.x * 256 + threadIdx.x;
    if (i < E) {
        int p = off[dst[i]] + (int)rel[i];
        out[i] = (sc[p] - mn) * inv;
    }
}

extern "C" void kernel_launch(void* const* d_in, const int* in_sizes, int n_in,
                              void* d_out, int out_size, void* d_ws, size_t ws_size,
                              hipStream_t stream) {
    const float* x   = (const float*)d_in[0];
    const int*   src = (const int*)d_in[1];
    const int*   dst = (const int*)d_in[2];
    const float* Ws1 = (const float*)d_in[3];
    const float* Wn1 = (const float*)d_in[4];
    const float* b1  = (const float*)d_in[5];
    const float* Ws2 = (const float*)d_in[6];
    const float* Wn2 = (const float*)d_in[7];
    const float* b2  = (const float*)d_in[8];

    int N = in_sizes[0] / F;   // 100000
    int E = in_sizes[1];       // 1600000
    float* out = (float*)d_out;

    int nbN = (N + 255) / 256;
    int nbE = (E + 255) / 256;
    int nbEdgeBlocks = (N + 3) / 4;       // 25000
    int NF4 = N * F / 4;

    // workspace layout (4-byte elements)
    int* off  = (int*)d_ws;                  // N
    int* cnt  = off + N;                     // N
    int* srcS = cnt + N;                     // E
    ushort* rel = (ushort*)(srcS + E);       // E ushorts = E/2 words
    float* sc = (float*)((int*)rel + E / 2); // E
    int* bsum = (int*)(sc + E);              // 1024
    float* rdeg = (float*)(bsum + 1024);     // N
    float* mmf = (float*)(rdeg + N);         // 2 (+2 pad)
    float2* pmm = (float2*)(mmf + 4);        // 25600 float2
    uint* Wtb = (uint*)(pmm + 25600);        // 32768 uints (frag-major)
    size_t elemOff = 3 * (size_t)N + 2 * (size_t)E + (size_t)E / 2 + 1024 + 4 + 51200 + 32768;
    elemOff = (elemOff + 3) & ~(size_t)3;    // 16B align
    uint* xb   = (uint*)d_ws + elemOff;      // N*64
    uint* msgb = xb + (size_t)N * 64;        // N*64
    uint* h1b  = msgb + (size_t)N * 64;      // N*64
    uint* h2b  = h1b + (size_t)N * 64;       // N*64

    // init
    (void)hipMemsetAsync(cnt, 0, (size_t)N * sizeof(int), stream);

    // CSR rank + prep fused (independent work), then scan + atomic-free fill
    int nbPrep = (NF4 + 4 * 16384 + 255) / 256;
    rank_prep<<<nbE + nbPrep, 256, 0, stream>>>(dst, cnt, rel, E, nbE,
                                                x, Ws1, Wn1, Ws2, Wn2, xb, (ushort*)Wtb, NF4);
    scan_block<<<nbN, 256, 0, stream>>>(cnt, off, bsum, N);
    scan_sums<<<1, 512, 0, stream>>>(bsum, nbN);
    scan_add_rdeg<<<nbN, 256, 0, stream>>>(off, bsum, cnt, rdeg, N);
    fill_kernel<<<nbE, 256, 0, stream>>>(src, dst, off, rel, srcS, E);

    // layer 1
    agg_gather<<<(N + 3) / 4, 256, 0, stream>>>(xb, off, srcS, rdeg, msgb, N, E);
    sage_mfma<<<(N + 63) / 64, 256, 0, stream>>>(xb, msgb, Wtb, b1, (ushort*)h1b, N);

    // layer 2
    agg_gather<<<(N + 3) / 4, 256, 0, stream>>>(h1b, off, srcS, rdeg, msgb, N, E);
    sage_mfma<<<(N + 63) / 64, 256, 0, stream>>>(h1b, msgb, Wtb + 16384, b2, (ushort*)h2b, N);

    // edge scores via MFMA (CSR order + per-block partials) + final reduce + normalize
    edge_score_mfma<<<nbEdgeBlocks, 256, 0, stream>>>(h2b, off, srcS, sc, pmm, N, E);
    minmax_final<<<1, 1024, 0, stream>>>(pmm, mmf, nbEdgeBlocks);
    norm_kernel<<<(E + 255) / 256, 256, 0, stream>>>(sc, dst, rel, off, out, mmf, E);
}